// Round 5
// baseline (342.672 us; speedup 1.0000x reference)
//
#include <hip/hip_runtime.h>
#include <hip/hip_bf16.h>
#include <math.h>

// GCN 2-layer: x[N,128] @ W1[128,128] -> gather/scatter norm agg -> +b1,relu
//              -> @ W2[128,64] -> agg -> +b2 -> log_softmax
// N=50000, E=1,600,000 (+N self loops handled analytically)
// - Gathered feature tables (xW1, hW2) in bf16.
// - Aggregation in channel-split passes: per-pass gather table = 3.2MB fits the
//   4MB per-XCD L2, turning the random gather from fabric traffic into L2 hits.
// - Graph build with zero per-edge global atomics (LDS-histogram binning).

typedef unsigned int uint;
typedef unsigned short ushort_t;

#define BSH 7                    // bucket shift: 128 nodes per bucket
#define NBMAX 400                // >= ceil(50000/128)=391
#define BIN_CHUNK 16384          // edges per k_bin block
#define CAP 6144                 // bin capacity per bucket (expected 4092, sd ~64)

__device__ inline float bf_lo(uint u) { return __uint_as_float(u << 16); }
__device__ inline float bf_hi(uint u) { return __uint_as_float(u & 0xffff0000u); }
__device__ inline ushort_t f2b(float f) {
    uint u = __float_as_uint(f);
    return (ushort_t)((u + 0x7fffu + ((u >> 16) & 1u)) >> 16);   // RNE
}

// ---------------- init: zero bucket counters ----------------
__global__ __launch_bounds__(256) void k_init(int* __restrict__ bktcnt, int nbk) {
    int i = blockIdx.x * 256 + threadIdx.x;
    if (i < nbk) bktcnt[i] = 0;
}

// ---------------- bin: bucket edges by dst>>BSH (LDS hist; block-segment writes) ----------------
// bucket b's region is bin[b*CAP .. ); entry = src | (dst & 127) << 17
__global__ __launch_bounds__(256) void k_bin(const int* __restrict__ esrc, const int* __restrict__ edst,
                                             int* __restrict__ bktcnt, uint* __restrict__ bin,
                                             int e, int nbk) {
    __shared__ int hist[NBMAX];
    __shared__ int segbase[NBMAX];
    int tid = threadIdx.x;
    int b0 = blockIdx.x * BIN_CHUNK;
    int b1 = min(b0 + BIN_CHUNK, e);
    for (int i = tid; i < nbk; i += 256) hist[i] = 0;
    __syncthreads();
    for (int i = b0 + tid * 4; i < b1; i += 1024) {
        if (i + 4 <= b1) {
            int4 d = *(const int4*)&edst[i];
            atomicAdd(&hist[d.x >> BSH], 1);
            atomicAdd(&hist[d.y >> BSH], 1);
            atomicAdd(&hist[d.z >> BSH], 1);
            atomicAdd(&hist[d.w >> BSH], 1);
        } else {
            for (int j = i; j < b1; ++j) atomicAdd(&hist[edst[j] >> BSH], 1);
        }
    }
    __syncthreads();
    for (int b = tid; b < nbk; b += 256) {
        int c = hist[b];
        int gb = c ? atomicAdd(&bktcnt[b], c) : 0;
        segbase[b] = b * CAP + gb;
        hist[b] = 0;  // reuse as local cursor
    }
    __syncthreads();
    for (int i = b0 + tid * 4; i < b1; i += 1024) {
        if (i + 4 <= b1) {
            int4 d = *(const int4*)&edst[i];
            int4 s = *(const int4*)&esrc[i];
            int bx = d.x >> BSH, by = d.y >> BSH, bz = d.z >> BSH, bw = d.w >> BSH;
            int px = atomicAdd(&hist[bx], 1);
            int py = atomicAdd(&hist[by], 1);
            int pz = atomicAdd(&hist[bz], 1);
            int pw = atomicAdd(&hist[bw], 1);
            bin[segbase[bx] + px] = (uint)s.x | ((uint)(d.x & 127) << 17);
            bin[segbase[by] + py] = (uint)s.y | ((uint)(d.y & 127) << 17);
            bin[segbase[bz] + pz] = (uint)s.z | ((uint)(d.z & 127) << 17);
            bin[segbase[bw] + pw] = (uint)s.w | ((uint)(d.w & 127) << 17);
        } else {
            for (int j = i; j < b1; ++j) {
                int d = edst[j], s = esrc[j];
                int b = d >> BSH;
                int p = atomicAdd(&hist[b], 1);
                bin[segbase[b] + p] = (uint)s | ((uint)(d & 127) << 17);
            }
        }
    }
}

// ---------------- scan of 391 bucket counts -> bucket CSR bases (one block) ----------------
__global__ __launch_bounds__(512) void k_scanBkt(const int* __restrict__ bktcnt, int* __restrict__ bktoff,
                                                 int nbk) {
    int tid = threadIdx.x;
    int v = (tid < nbk) ? bktcnt[tid] : 0;
    int x = v;
    for (int off = 1; off < 64; off <<= 1) {
        int y = __shfl_up(x, off);
        if ((tid & 63) >= off) x += y;
    }
    __shared__ int wt[8];
    if ((tid & 63) == 63) wt[tid >> 6] = x;
    __syncthreads();
    int w = tid >> 6, woff = 0;
    for (int k = 0; k < w; ++k) woff += wt[k];
    if (tid < nbk) bktoff[tid] = x - v + woff;
}

// ---------------- per-bucket: count/scan/scatter inside an L2-resident window ----------------
__global__ __launch_bounds__(256) void k_bucket(const uint* __restrict__ bin, const int* __restrict__ bktcnt,
                                                const int* __restrict__ bktoff,
                                                int* __restrict__ rowstart, int* __restrict__ cnt,
                                                float* __restrict__ dinv, int* __restrict__ csr, int n) {
    __shared__ int lcnt[1 << BSH];
    __shared__ int cur[1 << BSH];
    __shared__ int wt[4];
    int b = blockIdx.x;
    int tid = threadIdx.x;
    int lo = b << BSH;
    int nl = min(1 << BSH, n - lo);
    int m = bktcnt[b];
    int base = b * CAP;
    int obase = bktoff[b];
    if (tid < (1 << BSH)) lcnt[tid] = 0;
    __syncthreads();
    for (int i = tid; i < m; i += 256) {
        uint v = bin[base + i];
        atomicAdd(&lcnt[v >> 17], 1);
    }
    __syncthreads();
    int v = (tid < (1 << BSH)) ? lcnt[tid] : 0;
    int x = v;
    for (int off = 1; off < 64; off <<= 1) {
        int y = __shfl_up(x, off);
        if ((tid & 63) >= off) x += y;
    }
    if ((tid & 63) == 63) wt[tid >> 6] = x;
    __syncthreads();
    int excl = x - v + ((tid >= 64 && tid < 128) ? wt[0] : 0);
    if (tid < nl) {
        int node = lo + tid;
        rowstart[node] = obase + excl;
        cnt[node] = v;
        dinv[node] = rsqrtf((float)(v + 1));   // +1 self loop
        cur[tid] = obase + excl;
    }
    __syncthreads();
    for (int i = tid; i < m; i += 256) {
        uint en = bin[base + i];
        int dl = en >> 17;
        int p = atomicAdd(&cur[dl], 1);
        csr[p] = (int)(en & 0x1FFFFu);
    }
}

// ---------------- fp32 GEMM -> bf16 out: Y[n,COLS] = X[n,128] @ W[128,COLS] ----------------
template <int COLS, int BR, int TR, int TC>
__global__ __launch_bounds__(256) void k_gemm(const float* __restrict__ X, const float* __restrict__ W,
                                              ushort_t* __restrict__ Yb, int nrows) {
    constexpr int K = 128;
    constexpr int KH = 64;            // K half staged at a time
    constexpr int CT = COLS / TC;     // col-thread groups
    constexpr int RT = BR / TR;       // row-thread groups
    static_assert(CT * RT == 256, "bad tile");
    __shared__ float sW[KH * COLS];
    __shared__ float sX[BR][K + 1];   // +1 pad: kill stride-512B bank conflicts
    int tid = threadIdx.x;
    int rbase = blockIdx.x * BR;

    for (int i = tid * 4; i < BR * K; i += 1024) {
        int r = i >> 7, k = i & 127;
        float4 v = make_float4(0.f, 0.f, 0.f, 0.f);
        if (rbase + r < nrows) v = *(const float4*)&X[(size_t)(rbase + r) * K + k];
        sX[r][k + 0] = v.x; sX[r][k + 1] = v.y; sX[r][k + 2] = v.z; sX[r][k + 3] = v.w;
    }

    int ct = tid % CT, rt = tid / CT;
    int c0 = ct * TC, r0 = rt * TR;
    float acc[TR][TC] = {};

    for (int kb = 0; kb < K; kb += KH) {
        __syncthreads();
        for (int i = tid * 4; i < KH * COLS; i += 1024) {
            *(float4*)&sW[i] = *(const float4*)&W[kb * COLS + i];
        }
        __syncthreads();
#pragma unroll 4
        for (int k = 0; k < KH; ++k) {
            float xv[TR];
#pragma unroll
            for (int r = 0; r < TR; ++r) xv[r] = sX[r0 + r][kb + k];
#pragma unroll
            for (int c4 = 0; c4 < TC; c4 += 4) {
                float4 wv = *(float4*)&sW[k * COLS + c0 + c4];
#pragma unroll
                for (int r = 0; r < TR; ++r) {
                    acc[r][c4 + 0] = fmaf(xv[r], wv.x, acc[r][c4 + 0]);
                    acc[r][c4 + 1] = fmaf(xv[r], wv.y, acc[r][c4 + 1]);
                    acc[r][c4 + 2] = fmaf(xv[r], wv.z, acc[r][c4 + 2]);
                    acc[r][c4 + 3] = fmaf(xv[r], wv.w, acc[r][c4 + 3]);
                }
            }
        }
    }
#pragma unroll
    for (int r = 0; r < TR; ++r) {
        int row = rbase + r0 + r;
        if (row < nrows) {
            uint pk[TC / 2];
#pragma unroll
            for (int c2 = 0; c2 < TC; c2 += 2) {
                pk[c2 / 2] = (uint)f2b(acc[r][c2]) | ((uint)f2b(acc[r][c2 + 1]) << 16);
            }
            uint* dst = (uint*)&Yb[(size_t)row * COLS + c0];
#pragma unroll
            for (int q = 0; q < TC / 2; ++q) dst[q] = pk[q];
        }
    }
}

// ---- conv1 aggregation, quarter pass q: 32 channels (64B rows, 3.2MB table -> L2-resident) ----
// wave per node; 4 edge-groups x 16 lanes; unroll 2 -> 8 edges in flight.
__global__ __launch_bounds__(256) void k_agg1q(const uint* __restrict__ xw, const int* __restrict__ csr,
                                               const int* __restrict__ rowstart, const int* __restrict__ cnt,
                                               const float* __restrict__ dinv, const float* __restrict__ b1,
                                               float* __restrict__ h, int n, int q) {
    int i = blockIdx.x * 4 + (threadIdx.x >> 6);
    if (i >= n) return;
    int lane = threadIdx.x & 63;
    int g = lane >> 4;          // edge group 0..3
    int c = lane & 15;          // uint (2ch) index within quarter row
    const uint* tbl = xw + q * 16;
    float di = dinv[i];
    float ax = 0.f, ay = 0.f;
    if (g == 0) {
        uint a = tbl[(size_t)i * 64 + c];
        ax = bf_lo(a) * di; ay = bf_hi(a) * di;    // self loop
    }
    int beg = rowstart[i], m = cnt[i];
    int j = 0;
    for (; j + 8 <= m; j += 8) {
        int e0 = csr[beg + j + g];
        int e1 = csr[beg + j + 4 + g];
        float d0 = dinv[e0], d1 = dinv[e1];
        uint v0 = tbl[(size_t)e0 * 64 + c];
        uint v1 = tbl[(size_t)e1 * 64 + c];
        ax = fmaf(d0, bf_lo(v0), ax); ay = fmaf(d0, bf_hi(v0), ay);
        ax = fmaf(d1, bf_lo(v1), ax); ay = fmaf(d1, bf_hi(v1), ay);
    }
    for (; j < m; j += 4) {
        if (j + g < m) {
            int e0 = csr[beg + j + g];
            float d0 = dinv[e0];
            uint v0 = tbl[(size_t)e0 * 64 + c];
            ax = fmaf(d0, bf_lo(v0), ax); ay = fmaf(d0, bf_hi(v0), ay);
        }
    }
    ax += __shfl_xor(ax, 16); ay += __shfl_xor(ay, 16);
    ax += __shfl_xor(ax, 32); ay += __shfl_xor(ay, 32);
    if (g == 0) {
        int ch = q * 32 + 2 * c;
        float ox = fmaxf(fmaf(di, ax, b1[ch]), 0.f);
        float oy = fmaxf(fmaf(di, ay, b1[ch + 1]), 0.f);
        *(float2*)&h[(size_t)i * 128 + ch] = make_float2(ox, oy);
    }
}

// ---- conv2 aggregation, half pass q: 32 channels (64B rows, 3.2MB table), writes pre-softmax o --
__global__ __launch_bounds__(256) void k_agg2h(const uint* __restrict__ hw, const int* __restrict__ csr,
                                               const int* __restrict__ rowstart, const int* __restrict__ cnt,
                                               const float* __restrict__ dinv, const float* __restrict__ b2,
                                               float* __restrict__ o, int n, int q) {
    int i = blockIdx.x * 4 + (threadIdx.x >> 6);
    if (i >= n) return;
    int lane = threadIdx.x & 63;
    int g = lane >> 4;
    int c = lane & 15;
    const uint* tbl = hw + q * 16;          // row stride 32 uints (64ch bf16)
    float di = dinv[i];
    float ax = 0.f, ay = 0.f;
    if (g == 0) {
        uint a = tbl[(size_t)i * 32 + c];
        ax = bf_lo(a) * di; ay = bf_hi(a) * di;    // self loop
    }
    int beg = rowstart[i], m = cnt[i];
    int j = 0;
    for (; j + 8 <= m; j += 8) {
        int e0 = csr[beg + j + g];
        int e1 = csr[beg + j + 4 + g];
        float d0 = dinv[e0], d1 = dinv[e1];
        uint v0 = tbl[(size_t)e0 * 32 + c];
        uint v1 = tbl[(size_t)e1 * 32 + c];
        ax = fmaf(d0, bf_lo(v0), ax); ay = fmaf(d0, bf_hi(v0), ay);
        ax = fmaf(d1, bf_lo(v1), ax); ay = fmaf(d1, bf_hi(v1), ay);
    }
    for (; j < m; j += 4) {
        if (j + g < m) {
            int e0 = csr[beg + j + g];
            float d0 = dinv[e0];
            uint v0 = tbl[(size_t)e0 * 32 + c];
            ax = fmaf(d0, bf_lo(v0), ax); ay = fmaf(d0, bf_hi(v0), ay);
        }
    }
    ax += __shfl_xor(ax, 16); ay += __shfl_xor(ay, 16);
    ax += __shfl_xor(ax, 32); ay += __shfl_xor(ay, 32);
    if (g == 0) {
        int ch = q * 32 + 2 * c;
        float ox = fmaf(di, ax, b2[ch]);
        float oy = fmaf(di, ay, b2[ch + 1]);
        *(float2*)&o[(size_t)i * 64 + ch] = make_float2(ox, oy);
    }
}

// ---------------- log_softmax over 64 channels: wave per node ----------------
__global__ __launch_bounds__(256) void k_softmax(const float* __restrict__ o, float* __restrict__ out, int n) {
    int i = blockIdx.x * 4 + (threadIdx.x >> 6);
    if (i >= n) return;
    int lane = threadIdx.x & 63;
    float v = o[(size_t)i * 64 + lane];
    float mx = v;
    for (int off = 32; off; off >>= 1) mx = fmaxf(mx, __shfl_xor(mx, off));
    float ex = expf(v - mx);
    float sum = ex;
    for (int off = 32; off; off >>= 1) sum += __shfl_xor(sum, off);
    out[(size_t)i * 64 + lane] = v - mx - logf(sum);
}

extern "C" void kernel_launch(void* const* d_in, const int* in_sizes, int n_in,
                              void* d_out, int out_size, void* d_ws, size_t ws_size,
                              hipStream_t stream) {
    const float* x  = (const float*)d_in[0];
    const int* eidx = (const int*)d_in[1];
    const float* W1 = (const float*)d_in[2];
    const float* b1 = (const float*)d_in[3];
    const float* W2 = (const float*)d_in[4];
    const float* b2 = (const float*)d_in[5];
    float* out = (float*)d_out;

    const int n = in_sizes[0] / 128;       // 50000
    const int e = in_sizes[1] / 2;         // 1,600,000
    const int* esrc = eidx;
    const int* edst = eidx + e;
    const int nbk = (n + (1 << BSH) - 1) >> BSH;   // 391 buckets

    // workspace carve-up (256B aligned)
    size_t off = 0;
    auto carve = [&](size_t bytes) {
        void* p = (char*)d_ws + off;
        off += (bytes + 255) & ~(size_t)255;
        return p;
    };
    ushort_t* xW1  = (ushort_t*)carve((size_t)n * 128 * 2);   // bf16; reused as o[N][64] f32 later
    float* h       = (float*)carve((size_t)n * 128 * 4);
    ushort_t* hW2  = (ushort_t*)carve((size_t)n * 64 * 2);    // bf16
    int*   cnt     = (int*)carve((size_t)n * 4);
    float* dinv    = (float*)carve((size_t)n * 4);
    int*   rowstart= (int*)carve((size_t)n * 4);
    int*   bktcnt  = (int*)carve((size_t)nbk * 4);
    int*   bktoff  = (int*)carve((size_t)nbk * 4);
    uint*  bin     = (uint*)carve((size_t)nbk * CAP * 4);
    int*   csr     = (int*)carve((size_t)e * 4);
    float* o       = (float*)xW1;          // alias: xW1 dead after agg1 passes; sizes match (12.8MB)
    (void)ws_size;

    const int nbBin  = (e + BIN_CHUNK - 1) / BIN_CHUNK;
    const int nbWave = (n + 3) / 4;                // 4 waves per 256-block

    k_init<<<(nbk + 255) / 256, 256, 0, stream>>>(bktcnt, nbk);
    k_bin<<<nbBin, 256, 0, stream>>>(esrc, edst, bktcnt, bin, e, nbk);
    k_scanBkt<<<1, 512, 0, stream>>>(bktcnt, bktoff, nbk);
    k_bucket<<<nbk, 256, 0, stream>>>(bin, bktcnt, bktoff, rowstart, cnt, dinv, csr, n);

    // conv1: xW1 = bf16(x @ W1)  (128 -> 128)
    k_gemm<128, 32, 2, 8><<<(n + 31) / 32, 256, 0, stream>>>(x, W1, xW1, n);
    for (int q = 0; q < 4; ++q)
        k_agg1q<<<nbWave, 256, 0, stream>>>((const uint*)xW1, csr, rowstart, cnt, dinv, b1, h, n, q);

    // conv2: hW2 = bf16(h @ W2)  (128 -> 64)
    k_gemm<64, 64, 2, 8><<<(n + 63) / 64, 256, 0, stream>>>(h, W2, hW2, n);
    for (int q = 0; q < 2; ++q)
        k_agg2h<<<nbWave, 256, 0, stream>>>((const uint*)hW2, csr, rowstart, cnt, dinv, b2, o, n, q);
    k_softmax<<<nbWave, 256, 0, stream>>>(o, out, n);
}

// Round 6
// 188.219 us; speedup vs baseline: 1.8206x; 1.8206x over previous
//
#include <hip/hip_runtime.h>
#include <hip/hip_bf16.h>
#include <math.h>

// GCN 2-layer: x[N,128] @ W1[128,128] -> gather/scatter norm agg -> +b1,relu
//              -> @ W2[128,64] -> agg -> +b2 -> log_softmax
// N=50000, E=1,600,000 (+N self loops handled analytically)
// - GEMMs: bf16 MFMA (16x16x32), XOR-swizzled LDS, W pre-transposed to bf16.
// - Gathered feature tables (xW1, hW2) and h in bf16.
// - Full-row aggregation (wave per node), fused bias/relu/log_softmax.
// - Graph build with zero per-edge global atomics (LDS-histogram binning).

typedef unsigned int uint;
typedef unsigned short ushort_t;
typedef __attribute__((ext_vector_type(8))) short bf16x8;
typedef __attribute__((ext_vector_type(4))) float f32x4;

#define BSH 7                    // bucket shift: 128 nodes per bucket
#define NBMAX 400                // >= ceil(50000/128)=391
#define BIN_CHUNK 16384          // edges per k_bin block
#define CAP 6144                 // bin capacity per bucket (expected 4092, sd ~64)

__device__ inline float bf_lo(uint u) { return __uint_as_float(u << 16); }
__device__ inline float bf_hi(uint u) { return __uint_as_float(u & 0xffff0000u); }
__device__ inline ushort_t f2b(float f) {
    uint u = __float_as_uint(f);
    return (ushort_t)((u + 0x7fffu + ((u >> 16) & 1u)) >> 16);   // RNE
}
__device__ inline float b2f(ushort_t s) { return __uint_as_float((uint)s << 16); }

// ---------------- init: zero bucket counters ----------------
__global__ __launch_bounds__(256) void k_init(int* __restrict__ bktcnt, int nbk) {
    int i = blockIdx.x * 256 + threadIdx.x;
    if (i < nbk) bktcnt[i] = 0;
}

// ---------------- bin: bucket edges by dst>>BSH (LDS hist; block-segment writes) ----------------
__global__ __launch_bounds__(256) void k_bin(const int* __restrict__ esrc, const int* __restrict__ edst,
                                             int* __restrict__ bktcnt, uint* __restrict__ bin,
                                             int e, int nbk) {
    __shared__ int hist[NBMAX];
    __shared__ int segbase[NBMAX];
    int tid = threadIdx.x;
    int b0 = blockIdx.x * BIN_CHUNK;
    int b1 = min(b0 + BIN_CHUNK, e);
    for (int i = tid; i < nbk; i += 256) hist[i] = 0;
    __syncthreads();
    for (int i = b0 + tid * 4; i < b1; i += 1024) {
        if (i + 4 <= b1) {
            int4 d = *(const int4*)&edst[i];
            atomicAdd(&hist[d.x >> BSH], 1);
            atomicAdd(&hist[d.y >> BSH], 1);
            atomicAdd(&hist[d.z >> BSH], 1);
            atomicAdd(&hist[d.w >> BSH], 1);
        } else {
            for (int j = i; j < b1; ++j) atomicAdd(&hist[edst[j] >> BSH], 1);
        }
    }
    __syncthreads();
    for (int b = tid; b < nbk; b += 256) {
        int c = hist[b];
        int gb = c ? atomicAdd(&bktcnt[b], c) : 0;
        segbase[b] = b * CAP + gb;
        hist[b] = 0;  // reuse as local cursor
    }
    __syncthreads();
    for (int i = b0 + tid * 4; i < b1; i += 1024) {
        if (i + 4 <= b1) {
            int4 d = *(const int4*)&edst[i];
            int4 s = *(const int4*)&esrc[i];
            int bx = d.x >> BSH, by = d.y >> BSH, bz = d.z >> BSH, bw = d.w >> BSH;
            int px = atomicAdd(&hist[bx], 1);
            int py = atomicAdd(&hist[by], 1);
            int pz = atomicAdd(&hist[bz], 1);
            int pw = atomicAdd(&hist[bw], 1);
            bin[segbase[bx] + px] = (uint)s.x | ((uint)(d.x & 127) << 17);
            bin[segbase[by] + py] = (uint)s.y | ((uint)(d.y & 127) << 17);
            bin[segbase[bz] + pz] = (uint)s.z | ((uint)(d.z & 127) << 17);
            bin[segbase[bw] + pw] = (uint)s.w | ((uint)(d.w & 127) << 17);
        } else {
            for (int j = i; j < b1; ++j) {
                int d = edst[j], s = esrc[j];
                int b = d >> BSH;
                int p = atomicAdd(&hist[b], 1);
                bin[segbase[b] + p] = (uint)s | ((uint)(d & 127) << 17);
            }
        }
    }
}

// ---------------- scan of 391 bucket counts -> bucket CSR bases (one block) ----------------
__global__ __launch_bounds__(512) void k_scanBkt(const int* __restrict__ bktcnt, int* __restrict__ bktoff,
                                                 int nbk) {
    int tid = threadIdx.x;
    int v = (tid < nbk) ? bktcnt[tid] : 0;
    int x = v;
    for (int off = 1; off < 64; off <<= 1) {
        int y = __shfl_up(x, off);
        if ((tid & 63) >= off) x += y;
    }
    __shared__ int wt[8];
    if ((tid & 63) == 63) wt[tid >> 6] = x;
    __syncthreads();
    int w = tid >> 6, woff = 0;
    for (int k = 0; k < w; ++k) woff += wt[k];
    if (tid < nbk) bktoff[tid] = x - v + woff;
}

// ---------------- per-bucket: count/scan/scatter inside an L2-resident window ----------------
__global__ __launch_bounds__(256) void k_bucket(const uint* __restrict__ bin, const int* __restrict__ bktcnt,
                                                const int* __restrict__ bktoff,
                                                int* __restrict__ rowstart, int* __restrict__ cnt,
                                                float* __restrict__ dinv, int* __restrict__ csr, int n) {
    __shared__ int lcnt[1 << BSH];
    __shared__ int cur[1 << BSH];
    __shared__ int wt[4];
    int b = blockIdx.x;
    int tid = threadIdx.x;
    int lo = b << BSH;
    int nl = min(1 << BSH, n - lo);
    int m = bktcnt[b];
    int base = b * CAP;
    int obase = bktoff[b];
    if (tid < (1 << BSH)) lcnt[tid] = 0;
    __syncthreads();
    for (int i = tid; i < m; i += 256) {
        uint v = bin[base + i];
        atomicAdd(&lcnt[v >> 17], 1);
    }
    __syncthreads();
    int v = (tid < (1 << BSH)) ? lcnt[tid] : 0;
    int x = v;
    for (int off = 1; off < 64; off <<= 1) {
        int y = __shfl_up(x, off);
        if ((tid & 63) >= off) x += y;
    }
    if ((tid & 63) == 63) wt[tid >> 6] = x;
    __syncthreads();
    int excl = x - v + ((tid >= 64 && tid < 128) ? wt[0] : 0);
    if (tid < nl) {
        int node = lo + tid;
        rowstart[node] = obase + excl;
        cnt[node] = v;
        dinv[node] = rsqrtf((float)(v + 1));   // +1 self loop
        cur[tid] = obase + excl;
    }
    __syncthreads();
    for (int i = tid; i < m; i += 256) {
        uint en = bin[base + i];
        int dl = en >> 17;
        int p = atomicAdd(&cur[dl], 1);
        csr[p] = (int)(en & 0x1FFFFu);
    }
}

// ---------------- one-time weight transpose+cvt: W1[128x128]->W1t[n][k], W2[128x64]->W2t[n][k] ----
__global__ __launch_bounds__(256) void k_cvtW(const float* __restrict__ W1, const float* __restrict__ W2,
                                              ushort_t* __restrict__ W1t, ushort_t* __restrict__ W2t) {
    int i = blockIdx.x * 256 + threadIdx.x;
    if (i < 16384) {
        int k = i >> 7, nn = i & 127;
        W1t[nn * 128 + k] = f2b(W1[k * 128 + nn]);
    } else if (i < 16384 + 8192) {
        int j = i - 16384;
        int k = j >> 6, nn = j & 63;
        W2t[nn * 128 + k] = f2b(W2[k * 64 + nn]);
    }
}

// ---------------- MFMA bf16 GEMM: Y[n,COLS] = X[n,128] @ W[128,COLS], Y in bf16 ----------------
// BR=64 rows/block, 4 waves x 16 rows; full K=128 in LDS; Wt = W^T[n][k] bf16 in global.
// LDS rows XOR-swizzled (byte ^= (row&7)<<4) for conflict-free ds_read_b128.
template <int COLS, bool XBF16>
__global__ __launch_bounds__(256) void k_mgemm(const void* __restrict__ Xv, const ushort_t* __restrict__ Wt,
                                               ushort_t* __restrict__ Y, int nrows) {
    constexpr int NT = COLS / 16;                  // col tiles
    __shared__ ushort_t lsX[64 * 128];             // 16KB
    __shared__ ushort_t lsW[COLS * 128];           // 32KB (COLS=128) / 16KB (64)
    int tid = threadIdx.x;
    int rbase = blockIdx.x * 64;

    // stage X tile: 8192 bf16, 8 per thread-iter, swizzled 16B stores
#pragma unroll
    for (int it = 0; it < 4; ++it) {
        int idx = (tid + it * 256) * 8;
        int r = idx >> 7, c = idx & 127;
        int grow = rbase + r;
        uint4 pv = make_uint4(0, 0, 0, 0);
        if (grow < nrows) {
            if (XBF16) {
                pv = *(const uint4*)((const ushort_t*)Xv + (size_t)grow * 128 + c);
            } else {
                const float* xp = (const float*)Xv + (size_t)grow * 128 + c;
                float4 a = *(const float4*)xp;
                float4 b = *(const float4*)(xp + 4);
                pv.x = (uint)f2b(a.x) | ((uint)f2b(a.y) << 16);
                pv.y = (uint)f2b(a.z) | ((uint)f2b(a.w) << 16);
                pv.z = (uint)f2b(b.x) | ((uint)f2b(b.y) << 16);
                pv.w = (uint)f2b(b.z) | ((uint)f2b(b.w) << 16);
            }
        }
        int boff = (r * 256 + c * 2) ^ ((r & 7) << 4);
        *(uint4*)((char*)lsX + boff) = pv;
    }
    // stage W^T: COLS*128 bf16 contiguous from global, swizzled
#pragma unroll
    for (int it = 0; it < NT; ++it) {
        int idx = (tid + it * 256) * 8;
        int nr = idx >> 7, k = idx & 127;
        uint4 v = *(const uint4*)&Wt[nr * 128 + k];
        int boff = (nr * 256 + k * 2) ^ ((nr & 7) << 4);
        *(uint4*)((char*)lsW + boff) = v;
    }
    __syncthreads();

    int w = tid >> 6, l = tid & 63;
    int lr = l & 15, lg = l >> 4;
    int xrow = w * 16 + lr;
    bf16x8 a[4];
#pragma unroll
    for (int ks = 0; ks < 4; ++ks) {
        int boff = (xrow * 256 + (ks * 32 + lg * 8) * 2) ^ ((xrow & 7) << 4);
        a[ks] = *(const bf16x8*)((const char*)lsX + boff);
    }
    f32x4 acc[NT];
#pragma unroll
    for (int ct = 0; ct < NT; ++ct) {
        acc[ct] = (f32x4){0.f, 0.f, 0.f, 0.f};
#pragma unroll
        for (int ks = 0; ks < 4; ++ks) {
            int wrow = ct * 16 + lr;
            int boff = (wrow * 256 + (ks * 32 + lg * 8) * 2) ^ ((wrow & 7) << 4);
            bf16x8 b = *(const bf16x8*)((const char*)lsW + boff);
            acc[ct] = __builtin_amdgcn_mfma_f32_16x16x32_bf16(a[ks], b, acc[ct], 0, 0, 0);
        }
    }
    // C-write: row = rbase + w*16 + lg*4 + r, col = ct*16 + lr  [m89 layout]
#pragma unroll
    for (int ct = 0; ct < NT; ++ct) {
#pragma unroll
        for (int r = 0; r < 4; ++r) {
            int row = rbase + w * 16 + lg * 4 + r;
            if (row < nrows) Y[(size_t)row * COLS + ct * 16 + lr] = f2b(acc[ct][r]);
        }
    }
}

// ------- conv1 aggregation: wave per node, 2 bf16 ch/lane (128 ch), bf16 gather + bias + relu -----
// writes h in bf16 (packed uint) for direct consumption by the MFMA GEMM2.
__global__ __launch_bounds__(256) void k_agg1(const uint* __restrict__ xw,   // bf16x2 per uint, 64/row
                                              const int* __restrict__ csr,
                                              const int* __restrict__ rowstart, const int* __restrict__ cnt,
                                              const float* __restrict__ dinv, const float* __restrict__ b1,
                                              uint* __restrict__ h, int n) {
    int i = blockIdx.x * 4 + (threadIdx.x >> 6);
    int lane = threadIdx.x & 63;
    if (i >= n) return;
    float di = dinv[i];
    uint a = xw[(size_t)i * 64 + lane];
    float accx = bf_lo(a) * di, accy = bf_hi(a) * di;   // self loop
    int beg = rowstart[i], m = cnt[i];
    int j = 0;
    for (; j + 4 <= m; j += 4) {
        int s0 = csr[beg + j], s1 = csr[beg + j + 1], s2 = csr[beg + j + 2], s3 = csr[beg + j + 3];
        float d0 = dinv[s0], d1 = dinv[s1], d2 = dinv[s2], d3 = dinv[s3];
        uint v0 = xw[(size_t)s0 * 64 + lane];
        uint v1 = xw[(size_t)s1 * 64 + lane];
        uint v2 = xw[(size_t)s2 * 64 + lane];
        uint v3 = xw[(size_t)s3 * 64 + lane];
        accx = fmaf(d0, bf_lo(v0), accx); accy = fmaf(d0, bf_hi(v0), accy);
        accx = fmaf(d1, bf_lo(v1), accx); accy = fmaf(d1, bf_hi(v1), accy);
        accx = fmaf(d2, bf_lo(v2), accx); accy = fmaf(d2, bf_hi(v2), accy);
        accx = fmaf(d3, bf_lo(v3), accx); accy = fmaf(d3, bf_hi(v3), accy);
    }
    for (; j < m; ++j) {
        int s0 = csr[beg + j];
        float d0 = dinv[s0];
        uint v0 = xw[(size_t)s0 * 64 + lane];
        accx = fmaf(d0, bf_lo(v0), accx); accy = fmaf(d0, bf_hi(v0), accy);
    }
    float2 bb = ((const float2*)b1)[lane];
    float ox = fmaxf(fmaf(di, accx, bb.x), 0.f);
    float oy = fmaxf(fmaf(di, accy, bb.y), 0.f);
    h[(size_t)i * 64 + lane] = (uint)f2b(ox) | ((uint)f2b(oy) << 16);
}

// ---- conv2 aggregation: wave per node, 1 bf16 ch/lane (64 ch), bf16 gather + bias + log_softmax --
__global__ __launch_bounds__(256) void k_agg2(const ushort_t* __restrict__ hw,
                                              const int* __restrict__ csr,
                                              const int* __restrict__ rowstart, const int* __restrict__ cnt,
                                              const float* __restrict__ dinv, const float* __restrict__ b2,
                                              float* __restrict__ out, int n) {
    int i = blockIdx.x * 4 + (threadIdx.x >> 6);
    int lane = threadIdx.x & 63;
    if (i >= n) return;
    float di = dinv[i];
    float acc = b2f(hw[(size_t)i * 64 + lane]) * di;   // self loop
    int beg = rowstart[i], m = cnt[i];
    int j = 0;
    for (; j + 4 <= m; j += 4) {
        int s0 = csr[beg + j], s1 = csr[beg + j + 1], s2 = csr[beg + j + 2], s3 = csr[beg + j + 3];
        float d0 = dinv[s0], d1 = dinv[s1], d2 = dinv[s2], d3 = dinv[s3];
        float v0 = b2f(hw[(size_t)s0 * 64 + lane]);
        float v1 = b2f(hw[(size_t)s1 * 64 + lane]);
        float v2 = b2f(hw[(size_t)s2 * 64 + lane]);
        float v3 = b2f(hw[(size_t)s3 * 64 + lane]);
        acc = fmaf(d0, v0, acc);
        acc = fmaf(d1, v1, acc);
        acc = fmaf(d2, v2, acc);
        acc = fmaf(d3, v3, acc);
    }
    for (; j < m; ++j) {
        int s0 = csr[beg + j];
        acc = fmaf(dinv[s0], b2f(hw[(size_t)s0 * 64 + lane]), acc);
    }
    float o = fmaf(di, acc, b2[lane]);
    // log_softmax across the 64 lanes
    float mx = o;
    for (int off = 32; off; off >>= 1) mx = fmaxf(mx, __shfl_xor(mx, off));
    float ex = expf(o - mx);
    float sum = ex;
    for (int off = 32; off; off >>= 1) sum += __shfl_xor(sum, off);
    out[(size_t)i * 64 + lane] = o - mx - logf(sum);
}

extern "C" void kernel_launch(void* const* d_in, const int* in_sizes, int n_in,
                              void* d_out, int out_size, void* d_ws, size_t ws_size,
                              hipStream_t stream) {
    const float* x  = (const float*)d_in[0];
    const int* eidx = (const int*)d_in[1];
    const float* W1 = (const float*)d_in[2];
    const float* b1 = (const float*)d_in[3];
    const float* W2 = (const float*)d_in[4];
    const float* b2 = (const float*)d_in[5];
    float* out = (float*)d_out;

    const int n = in_sizes[0] / 128;       // 50000
    const int e = in_sizes[1] / 2;         // 1,600,000
    const int* esrc = eidx;
    const int* edst = eidx + e;
    const int nbk = (n + (1 << BSH) - 1) >> BSH;   // 391 buckets

    // workspace carve-up (256B aligned)
    size_t off = 0;
    auto carve = [&](size_t bytes) {
        void* p = (char*)d_ws + off;
        off += (bytes + 255) & ~(size_t)255;
        return p;
    };
    ushort_t* xW1  = (ushort_t*)carve((size_t)n * 128 * 2);   // bf16
    ushort_t* h    = (ushort_t*)carve((size_t)n * 128 * 2);   // bf16
    ushort_t* hW2  = (ushort_t*)carve((size_t)n * 64 * 2);    // bf16
    ushort_t* W1t  = (ushort_t*)carve(128 * 128 * 2);
    ushort_t* W2t  = (ushort_t*)carve(64 * 128 * 2);
    int*   cnt     = (int*)carve((size_t)n * 4);
    float* dinv    = (float*)carve((size_t)n * 4);
    int*   rowstart= (int*)carve((size_t)n * 4);
    int*   bktcnt  = (int*)carve((size_t)nbk * 4);
    int*   bktoff  = (int*)carve((size_t)nbk * 4);
    uint*  bin     = (uint*)carve((size_t)nbk * CAP * 4);
    int*   csr     = (int*)carve((size_t)e * 4);
    (void)ws_size;

    const int nbBin  = (e + BIN_CHUNK - 1) / BIN_CHUNK;
    const int nbWave = (n + 3) / 4;                // 4 waves per 256-block
    const int nbGemm = (n + 63) / 64;              // 64 rows per block

    k_init<<<(nbk + 255) / 256, 256, 0, stream>>>(bktcnt, nbk);
    k_bin<<<nbBin, 256, 0, stream>>>(esrc, edst, bktcnt, bin, e, nbk);
    k_scanBkt<<<1, 512, 0, stream>>>(bktcnt, bktoff, nbk);
    k_bucket<<<nbk, 256, 0, stream>>>(bin, bktcnt, bktoff, rowstart, cnt, dinv, csr, n);
    k_cvtW<<<96, 256, 0, stream>>>(W1, W2, W1t, W2t);

    // conv1: xW1 = bf16(x @ W1)  (128 -> 128), MFMA
    k_mgemm<128, false><<<nbGemm, 256, 0, stream>>>(x, W1t, xW1, n);
    k_agg1<<<nbWave, 256, 0, stream>>>((const uint*)xW1, csr, rowstart, cnt, dinv, b1, (uint*)h, n);

    // conv2: hW2 = bf16(h @ W2)  (128 -> 64), MFMA
    k_mgemm<64, true><<<nbGemm, 256, 0, stream>>>(h, W2t, hW2, n);
    k_agg2<<<nbWave, 256, 0, stream>>>(hW2, csr, rowstart, cnt, dinv, b2, out, n);
}